// Round 2
// baseline (88534.735 us; speedup 1.0000x reference)
//
#include <hip/hip_runtime.h>
#include <math.h>

#define BB 64    // batch
#define TT 1024  // seq len
#define DD 128   // input dim
#define HH 512   // hidden dim
#define NBLK 256
#define NTHR 256
#define DYN_LDS 131072  // 128 KiB: w_ih(49KB max) + w_hh(49KB) + 2 tiles(32KB)

// ---------------------------------------------------------------------------
// Persistent bidirectional GRU.
//   grid = 256 blocks, 1 per CU (128KB LDS forces 1/CU -> co-resident).
//   bid: dir = bid>>7, layer = (bid>>6)&1, jg = bid&63 -> block owns 8 j-dims,
//   all 64 batches. Wave (tid>>6) owns 2 j; lane (tid&63) = batch.
//   Weights LDS-resident for the whole kernel. h stored transposed [dim][b]
//   in ws so staging is a flat memcpy and stores are coalesced.
//   Steps separated by per-direction atomic barriers (128 blocks each).
//   Pipeline: step s runs L0 at t=s and L1 at t=s-1 (parity double buffer).
// ---------------------------------------------------------------------------

struct GP {
  const float* x;
  const float* Wih[4]; const float* Whh[4];
  const float* bih[4]; const float* bhh[4];
  float* h0;   // [2 dir][2 par][HH][BB]
  float* h1;
  int* bar;    // [dir][2]: counter, generation
};

__device__ __forceinline__ void stage_lin(float* __restrict__ tile,
                                          const float* __restrict__ src, int tid) {
  const float4* s = (const float4*)src;
  float4* d = (float4*)tile;
  #pragma unroll
  for (int i = 0; i < 4; ++i) d[tid + i * NTHR] = s[tid + i * NTHR];
}

__device__ __forceinline__ void stage_x(float* __restrict__ tile,
                                        const float* __restrict__ x,
                                        int tx, int k0, int tid) {
  const int b = tid & 63, dq = tid >> 6;           // 4 quads of 16 k
  const float* s = x + ((size_t)b * TT + tx) * DD + k0 + dq * 16;
  #pragma unroll
  for (int i = 0; i < 16; ++i) tile[(dq * 16 + i) * 64 + b] = s[i];
}

__device__ __forceinline__ void tile_mac(
    const float* __restrict__ tile, const float* __restrict__ W,
    const int Klen, const int k0, const int wj0, const int b,
    float& a00, float& a10, float& a20,
    float& a01, float& a11, float& a21) {
  const float* w0 = W + (size_t)(0 * 8 + wj0) * Klen + k0;
  const float* w1 = W + (size_t)(1 * 8 + wj0) * Klen + k0;
  const float* w2 = W + (size_t)(2 * 8 + wj0) * Klen + k0;
  #pragma unroll 4
  for (int kk = 0; kk < 64; kk += 4) {
    const float c0 = tile[(kk + 0) * 64 + b];
    const float c1 = tile[(kk + 1) * 64 + b];
    const float c2 = tile[(kk + 2) * 64 + b];
    const float c3 = tile[(kk + 3) * 64 + b];
    float4 v;
    v = *(const float4*)(w0 + kk);
    a00 += v.x * c0 + v.y * c1 + v.z * c2 + v.w * c3;
    v = *(const float4*)(w0 + Klen + kk);
    a01 += v.x * c0 + v.y * c1 + v.z * c2 + v.w * c3;
    v = *(const float4*)(w1 + kk);
    a10 += v.x * c0 + v.y * c1 + v.z * c2 + v.w * c3;
    v = *(const float4*)(w1 + Klen + kk);
    a11 += v.x * c0 + v.y * c1 + v.z * c2 + v.w * c3;
    v = *(const float4*)(w2 + kk);
    a20 += v.x * c0 + v.y * c1 + v.z * c2 + v.w * c3;
    v = *(const float4*)(w2 + Klen + kk);
    a21 += v.x * c0 + v.y * c1 + v.z * c2 + v.w * c3;
  }
}

// sense-reversing barrier among n blocks (one thread per block calls this)
__device__ __forceinline__ void dir_barrier(int* cnt, int* gen, int n) {
  const int g = __hip_atomic_load(gen, __ATOMIC_RELAXED, __HIP_MEMORY_SCOPE_AGENT);
  __threadfence();
  const int old = __hip_atomic_fetch_add(cnt, 1, __ATOMIC_ACQ_REL, __HIP_MEMORY_SCOPE_AGENT);
  if (old == n - 1) {
    __hip_atomic_store(cnt, 0, __ATOMIC_RELAXED, __HIP_MEMORY_SCOPE_AGENT);
    __hip_atomic_store(gen, g + 1, __ATOMIC_RELEASE, __HIP_MEMORY_SCOPE_AGENT);
  } else {
    while (__hip_atomic_load(gen, __ATOMIC_ACQUIRE, __HIP_MEMORY_SCOPE_AGENT) == g)
      __builtin_amdgcn_s_sleep(1);
  }
}

__global__ __launch_bounds__(NTHR) void gru_persist(GP p) {
  extern __shared__ float smem[];
  const int bid   = blockIdx.x;
  const int dir   = bid >> 7;
  const int rr    = bid & 127;
  const int layer = rr >> 6;
  const int jg    = rr & 63;
  const int jbase = jg * 8;
  const int Kin   = layer ? HH : DD;
  const int u     = dir * 2 + layer;

  float* w_ih  = smem;                 // [3][8][Kin]
  float* w_hh  = smem + 24 * Kin;      // [3][8][HH]
  float* tileA = w_hh + 24 * HH;       // [64][64]
  float* tileB = tileA + 4096;

  const int tid = threadIdx.x;
  const int b   = tid & 63;
  const int wv  = tid >> 6;
  const int wj0 = wv * 2;

  // ---- one-time: weights -> LDS ----
  {
    const float* Wih = p.Wih[u];
    for (int rw = 0; rw < 24; ++rw) {
      const int g = rw >> 3, jl = rw & 7;
      const float4* s = (const float4*)(Wih + (size_t)(g * HH + jbase + jl) * Kin);
      float4* d = (float4*)(w_ih + (size_t)rw * Kin);
      for (int i = tid; i < (Kin >> 2); i += NTHR) d[i] = s[i];
    }
    const float* Whh = p.Whh[u];
    for (int rw = 0; rw < 24; ++rw) {
      const int g = rw >> 3, jl = rw & 7;
      const float4* s = (const float4*)(Whh + (size_t)(g * HH + jbase + jl) * HH);
      float4* d = (float4*)(w_hh + (size_t)rw * HH);
      for (int i = tid; i < (HH >> 2); i += NTHR) d[i] = s[i];
    }
  }
  // ---- one-time: biases -> regs (wave-uniform j) ----
  const int ja = jbase + wj0, jb2 = ja + 1;
  const float* bih = p.bih[u];
  const float* bhh = p.bhh[u];
  const float br0 = bih[ja] + bhh[ja],                 br1 = bih[jb2] + bhh[jb2];
  const float bz0 = bih[HH + ja] + bhh[HH + ja],       bz1 = bih[HH + jb2] + bhh[HH + jb2];
  const float bi0 = bih[2 * HH + ja],                  bi1 = bih[2 * HH + jb2];
  const float bh0 = bhh[2 * HH + ja],                  bh1 = bhh[2 * HH + jb2];

  float* hown = layer ? p.h1 : p.h0;
  int* cnt = p.bar + dir * 2;
  int* gen = p.bar + dir * 2 + 1;
  __syncthreads();

  for (int s = 0; s <= TT; ++s) {
    const int pw = s & 1, pr = pw ^ 1;
    const bool active = layer ? (s >= 1) : (s < TT);
    if (active) {
      const int t = layer ? (s - 1) : s;
      const int tx = dir ? (TT - 1 - t) : t;
      const float* src1 = layer ? (p.h0 + (size_t)(dir * 2 + pr) * HH * BB) : nullptr;
      const float* src2 = hown + (size_t)(dir * 2 + pr) * HH * BB;
      float*       dst  = hown + (size_t)(dir * 2 + pw) * HH * BB;
      float ar0 = 0, az0 = 0, ai0 = 0, ah0 = 0;
      float ar1 = 0, az1 = 0, ai1 = 0, ah1 = 0;
      int pb = 0;
      // pass 1: input contribution (x for L0, L0-output for L1)
      if (layer) stage_lin(tileA, src1, tid); else stage_x(tileA, p.x, tx, 0, tid);
      __syncthreads();
      const int nt1 = layer ? 8 : 2;
      for (int i = 0; i < nt1; ++i) {
        float* cur = pb ? tileB : tileA;
        float* nxt = pb ? tileA : tileB;
        if (i + 1 < nt1) {
          if (layer) stage_lin(nxt, src1 + (size_t)(i + 1) * 4096, tid);
          else       stage_x(nxt, p.x, tx, 64, tid);
        } else {
          stage_lin(nxt, src2, tid);  // prefetch first tile of pass 2
        }
        tile_mac(cur, w_ih, Kin, i * 64, wj0, b, ar0, az0, ai0, ar1, az1, ai1);
        __syncthreads();
        pb ^= 1;
      }
      // pass 2: recurrent contribution
      for (int i = 0; i < 8; ++i) {
        float* cur = pb ? tileB : tileA;
        float* nxt = pb ? tileA : tileB;
        if (i + 1 < 8) stage_lin(nxt, src2 + (size_t)(i + 1) * 4096, tid);
        tile_mac(cur, w_hh, HH, i * 64, wj0, b, ar0, az0, ah0, ar1, az1, ah1);
        __syncthreads();
        pb ^= 1;
      }
      // gates + store (coalesced: [j][b])
      {
        const float hp0 = src2[(size_t)ja * BB + b];
        const float r0 = 1.f / (1.f + expf(-(ar0 + br0)));
        const float z0 = 1.f / (1.f + expf(-(az0 + bz0)));
        const float n0 = tanhf(ai0 + bi0 + r0 * (ah0 + bh0));
        dst[(size_t)ja * BB + b] = (1.f - z0) * n0 + z0 * hp0;
        const float hp1 = src2[(size_t)jb2 * BB + b];
        const float r1 = 1.f / (1.f + expf(-(ar1 + br1)));
        const float z1 = 1.f / (1.f + expf(-(az1 + bz1)));
        const float n1 = tanhf(ai1 + bi1 + r1 * (ah1 + bh1));
        dst[(size_t)jb2 * BB + b] = (1.f - z1) * n1 + z1 * hp1;
      }
    }
    __syncthreads();
    if (tid == 0) dir_barrier(cnt, gen, 128);
    __syncthreads();
  }
}

__global__ void zero_k(float* h, int* bar) {
  const int i = blockIdx.x * blockDim.x + threadIdx.x;
  if (i < 262144) h[i] = 0.f;
  if (i < 4) bar[i] = 0;
}

// hidden = [h0_f | h1_f | h0_b | h1_b]; h0 final parity 1, h1 final parity 0
__global__ void gather_hidden_k(const float* __restrict__ h0,
                                const float* __restrict__ h1,
                                float* __restrict__ fc_in) {
  const int idx = blockIdx.x * blockDim.x + threadIdx.x;  // 64*2048
  const int b   = idx >> 11;
  const int c   = idx & 2047;
  const int seg = c >> 9;
  const int cc  = c & 511;
  float v;
  if      (seg == 0) v = h0[(size_t)1 * HH * BB + cc * BB + b];
  else if (seg == 1) v = h1[(size_t)0 * HH * BB + cc * BB + b];
  else if (seg == 2) v = h0[(size_t)3 * HH * BB + cc * BB + b];
  else               v = h1[(size_t)2 * HH * BB + cc * BB + b];
  fc_in[idx] = v;
}

__global__ void fc_k(const float* __restrict__ in, const float* __restrict__ W,
                     const float* __restrict__ bias, float* __restrict__ out,
                     int K, int N, int leaky) {
  const int idx = blockIdx.x * blockDim.x + threadIdx.x;
  const int b = idx / N;
  const int n = idx - b * N;
  if (b >= BB) return;
  const float* ir = in + (size_t)b * K;
  const float* wr = W + (size_t)n * K;
  float acc = 0.f;
  for (int k = 0; k < K; k += 4) {
    const float4 a = *(const float4*)(ir + k);
    const float4 w = *(const float4*)(wr + k);
    acc += a.x * w.x + a.y * w.y + a.z * w.z + a.w * w.w;
  }
  acc += bias[n];
  if (leaky) acc = acc > 0.f ? acc : 0.01f * acc;
  out[idx] = acc;
}

extern "C" void kernel_launch(void* const* d_in, const int* in_sizes, int n_in,
                              void* d_out, int out_size, void* d_ws, size_t ws_size,
                              hipStream_t stream) {
  (void)in_sizes; (void)n_in; (void)out_size; (void)ws_size;

  GP P;
  P.x = (const float*)d_in[0];
  for (int dir = 0; dir < 2; ++dir) {
    for (int l = 0; l < 2; ++l) {
      const int base = 1 + (dir * 2 + l) * 4;
      const int u = dir * 2 + l;
      P.Wih[u] = (const float*)d_in[base + 0];
      P.Whh[u] = (const float*)d_in[base + 1];
      P.bih[u] = (const float*)d_in[base + 2];
      P.bhh[u] = (const float*)d_in[base + 3];
    }
  }
  const float* Wfc0 = (const float*)d_in[17];
  const float* bfc0 = (const float*)d_in[18];
  const float* Wfc1 = (const float*)d_in[19];
  const float* bfc1 = (const float*)d_in[20];
  const float* Wfc2 = (const float*)d_in[21];
  const float* bfc2 = (const float*)d_in[22];

  float* ws    = (float*)d_ws;
  float* h0    = ws;                  // 131072 f
  float* h1    = ws + 131072;        // 131072 f
  float* fc_in = ws + 262144;        // 131072 f
  float* fc1o  = ws + 393216;        //  65536 f
  float* fc2o  = ws + 458752;        //  32768 f
  int*   bar   = (int*)(ws + 491520);
  P.h0 = h0; P.h1 = h1; P.bar = bar;

  static int attr_done = 0;
  // idempotent, host-side only (not a stream op) — safe under graph capture
  hipFuncSetAttribute((const void*)gru_persist,
                      hipFuncAttributeMaxDynamicSharedMemorySize, DYN_LDS);
  (void)attr_done;

  hipLaunchKernelGGL(zero_k, dim3(1024), dim3(256), 0, stream, h0, bar);
  hipLaunchKernelGGL(gru_persist, dim3(NBLK), dim3(NTHR), DYN_LDS, stream, P);
  hipLaunchKernelGGL(gather_hidden_k, dim3(512), dim3(256), 0, stream, h0, h1, fc_in);
  hipLaunchKernelGGL(fc_k, dim3(256), dim3(256), 0, stream, fc_in, Wfc0, bfc0, fc1o, 2048, 1024, 1);
  hipLaunchKernelGGL(fc_k, dim3(128), dim3(256), 0, stream, fc1o, Wfc1, bfc1, fc2o, 1024, 512, 1);
  hipLaunchKernelGGL(fc_k, dim3(1),   dim3(256), 0, stream, fc2o, Wfc2, bfc2, (float*)d_out, 512, 1, 0);
}